// Round 1
// baseline (395.824 us; speedup 1.0000x reference)
//
#include <hip/hip_runtime.h>

// GatingNetwork: B=16384 rows, D=4096, H=OUT=7.
// One block per row, 256 threads, 16 f32 elements/thread/expert held in
// registers (4x float4). Fused: gate-MLP logits + 2-way softmax + combine,
// so each feature element is fetched from HBM exactly once.

constexpr int Dk  = 4096;
constexpr int Hk  = 7;
constexpr int NTH = 256;
constexpr int VPT = 4;   // float4 chunks per thread: 4*4*256 = 4096

__global__ __launch_bounds__(NTH, 4)
void gating_fused(const float* __restrict__ f1,
                  const float* __restrict__ f2,
                  const float* __restrict__ W1,
                  const float* __restrict__ b1,
                  const float* __restrict__ W2,
                  const float* __restrict__ b2,
                  float* __restrict__ out)
{
    const int row = blockIdx.x;
    const int t   = threadIdx.x;
    const long long base = (long long)row * Dk;

    const float4* __restrict__ f1v = reinterpret_cast<const float4*>(f1 + base);
    const float4* __restrict__ f2v = reinterpret_cast<const float4*>(f2 + base);

    float4 r1[VPT], r2[VPT];
    float acc1[Hk], acc2[Hk];
    #pragma unroll
    for (int j = 0; j < Hk; ++j) { acc1[j] = 0.f; acc2[j] = 0.f; }

    #pragma unroll
    for (int k = 0; k < VPT; ++k) {
        const int vi = k * NTH + t;          // float4 index within the row
        r1[k] = f1v[vi];
        r2[k] = f2v[vi];
        // W1 rows d..d+3 (d = 4*vi) are 28 consecutive floats, 112B-aligned.
        const float4* __restrict__ wv =
            reinterpret_cast<const float4*>(W1 + (long long)vi * 28);
        float4 w4[7];
        #pragma unroll
        for (int q = 0; q < 7; ++q) w4[q] = wv[q];
        const float* ws = reinterpret_cast<const float*>(w4);
        const float* x1 = reinterpret_cast<const float*>(&r1[k]);
        const float* x2 = reinterpret_cast<const float*>(&r2[k]);
        #pragma unroll
        for (int r = 0; r < 4; ++r) {
            #pragma unroll
            for (int j = 0; j < Hk; ++j) {
                acc1[j] = fmaf(x1[r], ws[r * 7 + j], acc1[j]);
                acc2[j] = fmaf(x2[r], ws[r * 7 + j], acc2[j]);
            }
        }
    }

    // 64-lane wave reduction of the 14 partial sums.
    #pragma unroll
    for (int j = 0; j < Hk; ++j) {
        #pragma unroll
        for (int off = 32; off >= 1; off >>= 1) {
            acc1[j] += __shfl_down(acc1[j], off);
            acc2[j] += __shfl_down(acc2[j], off);
        }
    }

    __shared__ float red[4][2 * Hk];
    __shared__ float alpha[2];
    const int wave = t >> 6;
    const int lane = t & 63;
    if (lane == 0) {
        #pragma unroll
        for (int j = 0; j < Hk; ++j) {
            red[wave][j]      = acc1[j];
            red[wave][Hk + j] = acc2[j];
        }
    }
    __syncthreads();

    if (t == 0) {
        // logit = mean_k( relu(h) @ W2[:,k] + b2[k] )
        //       = ( sum_j relu(h_j) * rowsumW2_j + sum(b2) ) / 7
        float l1 = 0.f, l2 = 0.f;
        #pragma unroll
        for (int j = 0; j < Hk; ++j) {
            float h1 = red[0][j] + red[1][j] + red[2][j] + red[3][j] + b1[j];
            float h2 = red[0][Hk + j] + red[1][Hk + j] + red[2][Hk + j]
                     + red[3][Hk + j] + b1[j];
            h1 = fmaxf(h1, 0.f);
            h2 = fmaxf(h2, 0.f);
            float s = 0.f;
            #pragma unroll
            for (int k2 = 0; k2 < Hk; ++k2) s += W2[j * Hk + k2];
            l1 = fmaf(h1, s, l1);
            l2 = fmaf(h2, s, l2);
        }
        float sb2 = 0.f;
        #pragma unroll
        for (int k2 = 0; k2 < Hk; ++k2) sb2 += b2[k2];
        l1 = (l1 + sb2) * (1.f / 7.f);
        l2 = (l2 + sb2) * (1.f / 7.f);
        const float a0 = 1.f / (1.f + expf(l2 - l1));
        alpha[0] = a0;
        alpha[1] = 1.f - a0;
    }
    __syncthreads();

    const float a0 = alpha[0];
    const float a1 = alpha[1];
    float4* __restrict__ ov = reinterpret_cast<float4*>(out + base);
    #pragma unroll
    for (int k = 0; k < VPT; ++k) {
        const int vi = k * NTH + t;
        float4 o;
        o.x = a0 * r1[k].x + a1 * r2[k].x;
        o.y = a0 * r1[k].y + a1 * r2[k].y;
        o.z = a0 * r1[k].z + a1 * r2[k].z;
        o.w = a0 * r1[k].w + a1 * r2[k].w;
        ov[vi] = o;
    }
}

extern "C" void kernel_launch(void* const* d_in, const int* in_sizes, int n_in,
                              void* d_out, int out_size, void* d_ws, size_t ws_size,
                              hipStream_t stream) {
    const float* f1 = (const float*)d_in[0];
    const float* f2 = (const float*)d_in[1];
    const float* W1 = (const float*)d_in[2];
    const float* b1 = (const float*)d_in[3];
    const float* W2 = (const float*)d_in[4];
    const float* b2 = (const float*)d_in[5];
    float* out = (float*)d_out;

    const int rows = in_sizes[0] / Dk;   // 16384
    gating_fused<<<rows, NTH, 0, stream>>>(f1, f2, W1, b1, W2, b2, out);
}

// Round 2
// 272.843 us; speedup vs baseline: 1.4507x; 1.4507x over previous
//
#include <hip/hip_runtime.h>

// GatingNetwork: B=16384 rows, D=4096, H=OUT=7.
// One block per row, 256 threads, 16 f32 elements/thread/expert in registers.
// Round 2: W1 is pre-transposed into d_ws ([7][4096]) by a prep kernel so the
// main kernel's weight loads are coalesced float4 (lanes stride 16B), fixing
// the R1 latency-bound profile (uncoalesced 112B-stride W1 loads).

constexpr int Dk  = 4096;
constexpr int Hk  = 7;
constexpr int NTH = 256;
constexpr int VPT = 4;   // float4 chunks per thread: 4*4*256 = 4096
constexpr size_t WS_NEEDED = (size_t)Hk * Dk * sizeof(float) + 16 * sizeof(float);

// ws layout: [0 .. 7*4096)  W1T (j-major: W1T[j*4096 + d] = W1[d*7 + j])
//            [7*4096 .. +7) b1
//            [+7 .. +14)    s_j = sum_k W2[j,k]
//            [+14]          sum(b2)
__global__ void gating_prep(const float* __restrict__ W1,
                            const float* __restrict__ b1,
                            const float* __restrict__ W2,
                            const float* __restrict__ b2,
                            float* __restrict__ ws)
{
    const int d = blockIdx.x * NTH + threadIdx.x;
    if (d < Dk) {
        #pragma unroll
        for (int j = 0; j < Hk; ++j)
            ws[j * Dk + d] = W1[d * Hk + j];
    }
    if (blockIdx.x == 0 && threadIdx.x == 0) {
        float* c = ws + Hk * Dk;
        #pragma unroll
        for (int j = 0; j < Hk; ++j) {
            c[j] = b1[j];
            float s = 0.f;
            #pragma unroll
            for (int k = 0; k < Hk; ++k) s += W2[j * Hk + k];
            c[Hk + j] = s;
        }
        float sb2 = 0.f;
        #pragma unroll
        for (int k = 0; k < Hk; ++k) sb2 += b2[k];
        c[14] = sb2;
    }
}

__global__ __launch_bounds__(NTH, 6)
void gating_fused(const float* __restrict__ f1,
                  const float* __restrict__ f2,
                  const float* __restrict__ W1T,   // [7][4096] in ws
                  const float* __restrict__ gc,    // ws + 7*4096: b1[7], s[7], sb2
                  float* __restrict__ out)
{
    const int row = blockIdx.x;
    const int t   = threadIdx.x;
    const long long base = (long long)row * Dk;

    const float4* __restrict__ f1v = reinterpret_cast<const float4*>(f1 + base);
    const float4* __restrict__ f2v = reinterpret_cast<const float4*>(f2 + base);
    const float4* __restrict__ wTv = reinterpret_cast<const float4*>(W1T);

    // Issue all feature loads first — deepest HBM overlap.
    float4 r1[VPT], r2[VPT];
    #pragma unroll
    for (int k = 0; k < VPT; ++k) {
        const int vi = k * NTH + t;
        r1[k] = f1v[vi];
        r2[k] = f2v[vi];
    }

    float acc1[Hk], acc2[Hk];
    #pragma unroll
    for (int j = 0; j < Hk; ++j) { acc1[j] = 0.f; acc2[j] = 0.f; }

    #pragma unroll
    for (int k = 0; k < VPT; ++k) {
        const int vi = k * NTH + t;              // float4 index within the row
        // W1T[j][4vi .. 4vi+3]: coalesced float4 per j (lanes stride 16B).
        float4 w[Hk];
        #pragma unroll
        for (int j = 0; j < Hk; ++j) w[j] = wTv[j * (Dk / 4) + vi];
        const float* x1 = reinterpret_cast<const float*>(&r1[k]);
        const float* x2 = reinterpret_cast<const float*>(&r2[k]);
        #pragma unroll
        for (int j = 0; j < Hk; ++j) {
            const float* wj = reinterpret_cast<const float*>(&w[j]);
            #pragma unroll
            for (int r = 0; r < 4; ++r) {
                acc1[j] = fmaf(x1[r], wj[r], acc1[j]);
                acc2[j] = fmaf(x2[r], wj[r], acc2[j]);
            }
        }
    }

    // 64-lane wave reduction of the 14 partial sums.
    #pragma unroll
    for (int j = 0; j < Hk; ++j) {
        #pragma unroll
        for (int off = 32; off >= 1; off >>= 1) {
            acc1[j] += __shfl_down(acc1[j], off);
            acc2[j] += __shfl_down(acc2[j], off);
        }
    }

    __shared__ float red[4][2 * Hk];
    __shared__ float alpha[2];
    const int wave = t >> 6;
    const int lane = t & 63;
    if (lane == 0) {
        #pragma unroll
        for (int j = 0; j < Hk; ++j) {
            red[wave][j]      = acc1[j];
            red[wave][Hk + j] = acc2[j];
        }
    }
    __syncthreads();

    if (t == 0) {
        // logit = ( sum_j relu(h_j) * s_j + sum(b2) ) / 7
        float l1 = 0.f, l2 = 0.f;
        #pragma unroll
        for (int j = 0; j < Hk; ++j) {
            const float b1j = gc[j];
            const float sj  = gc[Hk + j];
            float h1 = red[0][j] + red[1][j] + red[2][j] + red[3][j] + b1j;
            float h2 = red[0][Hk + j] + red[1][Hk + j] + red[2][Hk + j]
                     + red[3][Hk + j] + b1j;
            l1 = fmaf(fmaxf(h1, 0.f), sj, l1);
            l2 = fmaf(fmaxf(h2, 0.f), sj, l2);
        }
        const float sb2 = gc[14];
        l1 = (l1 + sb2) * (1.f / 7.f);
        l2 = (l2 + sb2) * (1.f / 7.f);
        const float a0 = 1.f / (1.f + expf(l2 - l1));
        alpha[0] = a0;
        alpha[1] = 1.f - a0;
    }
    __syncthreads();

    const float a0 = alpha[0];
    const float a1 = alpha[1];
    float4* __restrict__ ov = reinterpret_cast<float4*>(out + base);
    #pragma unroll
    for (int k = 0; k < VPT; ++k) {
        const int vi = k * NTH + t;
        float4 o;
        o.x = a0 * r1[k].x + a1 * r2[k].x;
        o.y = a0 * r1[k].y + a1 * r2[k].y;
        o.z = a0 * r1[k].z + a1 * r2[k].z;
        o.w = a0 * r1[k].w + a1 * r2[k].w;
        ov[vi] = o;
    }
}

// Fallback (ws too small): original direct-W1 path, still correct.
__global__ __launch_bounds__(NTH, 4)
void gating_fused_direct(const float* __restrict__ f1,
                         const float* __restrict__ f2,
                         const float* __restrict__ W1,
                         const float* __restrict__ b1,
                         const float* __restrict__ W2,
                         const float* __restrict__ b2,
                         float* __restrict__ out)
{
    const int row = blockIdx.x;
    const int t   = threadIdx.x;
    const long long base = (long long)row * Dk;

    const float4* __restrict__ f1v = reinterpret_cast<const float4*>(f1 + base);
    const float4* __restrict__ f2v = reinterpret_cast<const float4*>(f2 + base);

    float4 r1[VPT], r2[VPT];
    float acc1[Hk], acc2[Hk];
    #pragma unroll
    for (int j = 0; j < Hk; ++j) { acc1[j] = 0.f; acc2[j] = 0.f; }

    #pragma unroll
    for (int k = 0; k < VPT; ++k) {
        const int vi = k * NTH + t;
        r1[k] = f1v[vi];
        r2[k] = f2v[vi];
        const float4* wv = reinterpret_cast<const float4*>(W1 + (long long)vi * 28);
        float4 w4[7];
        #pragma unroll
        for (int q = 0; q < 7; ++q) w4[q] = wv[q];
        const float* ws = reinterpret_cast<const float*>(w4);
        const float* x1 = reinterpret_cast<const float*>(&r1[k]);
        const float* x2 = reinterpret_cast<const float*>(&r2[k]);
        #pragma unroll
        for (int r = 0; r < 4; ++r)
            #pragma unroll
            for (int j = 0; j < Hk; ++j) {
                acc1[j] = fmaf(x1[r], ws[r * 7 + j], acc1[j]);
                acc2[j] = fmaf(x2[r], ws[r * 7 + j], acc2[j]);
            }
    }
    #pragma unroll
    for (int j = 0; j < Hk; ++j)
        #pragma unroll
        for (int off = 32; off >= 1; off >>= 1) {
            acc1[j] += __shfl_down(acc1[j], off);
            acc2[j] += __shfl_down(acc2[j], off);
        }

    __shared__ float red[4][2 * Hk];
    __shared__ float alpha[2];
    const int wave = t >> 6;
    const int lane = t & 63;
    if (lane == 0)
        #pragma unroll
        for (int j = 0; j < Hk; ++j) {
            red[wave][j]      = acc1[j];
            red[wave][Hk + j] = acc2[j];
        }
    __syncthreads();

    if (t == 0) {
        float l1 = 0.f, l2 = 0.f;
        #pragma unroll
        for (int j = 0; j < Hk; ++j) {
            float h1 = red[0][j] + red[1][j] + red[2][j] + red[3][j] + b1[j];
            float h2 = red[0][Hk + j] + red[1][Hk + j] + red[2][Hk + j]
                     + red[3][Hk + j] + b1[j];
            float s = 0.f;
            #pragma unroll
            for (int k2 = 0; k2 < Hk; ++k2) s += W2[j * Hk + k2];
            l1 = fmaf(fmaxf(h1, 0.f), s, l1);
            l2 = fmaf(fmaxf(h2, 0.f), s, l2);
        }
        float sb2 = 0.f;
        #pragma unroll
        for (int k2 = 0; k2 < Hk; ++k2) sb2 += b2[k2];
        l1 = (l1 + sb2) * (1.f / 7.f);
        l2 = (l2 + sb2) * (1.f / 7.f);
        const float a0 = 1.f / (1.f + expf(l2 - l1));
        alpha[0] = a0;
        alpha[1] = 1.f - a0;
    }
    __syncthreads();

    const float a0 = alpha[0];
    const float a1 = alpha[1];
    float4* ov = reinterpret_cast<float4*>(out + base);
    #pragma unroll
    for (int k = 0; k < VPT; ++k) {
        const int vi = k * NTH + t;
        float4 o;
        o.x = a0 * r1[k].x + a1 * r2[k].x;
        o.y = a0 * r1[k].y + a1 * r2[k].y;
        o.z = a0 * r1[k].z + a1 * r2[k].z;
        o.w = a0 * r1[k].w + a1 * r2[k].w;
        ov[vi] = o;
    }
}

extern "C" void kernel_launch(void* const* d_in, const int* in_sizes, int n_in,
                              void* d_out, int out_size, void* d_ws, size_t ws_size,
                              hipStream_t stream) {
    const float* f1 = (const float*)d_in[0];
    const float* f2 = (const float*)d_in[1];
    const float* W1 = (const float*)d_in[2];
    const float* b1 = (const float*)d_in[3];
    const float* W2 = (const float*)d_in[4];
    const float* b2 = (const float*)d_in[5];
    float* out = (float*)d_out;
    const int rows = in_sizes[0] / Dk;   // 16384

    if (ws_size >= WS_NEEDED) {
        float* ws = (float*)d_ws;
        gating_prep<<<(Dk + NTH - 1) / NTH, NTH, 0, stream>>>(W1, b1, W2, b2, ws);
        gating_fused<<<rows, NTH, 0, stream>>>(f1, f2, ws, ws + Hk * Dk, out);
    } else {
        gating_fused_direct<<<rows, NTH, 0, stream>>>(f1, f2, W1, b1, W2, b2, out);
    }
}

// Round 3
// 248.115 us; speedup vs baseline: 1.5953x; 1.0997x over previous
//
#include <hip/hip_runtime.h>

// GatingNetwork: B=16384 rows, D=4096, H=OUT=7.
// R3: streaming two-phase fused kernel.
//  Pass 1: stream row pair (coalesced float4), accumulate 14 dot-partials,
//          stash d = f1-f2 in LDS (16 KB).  No feature registers held.
//  Epilogue: wave shuffle-reduce -> LDS -> ALL threads redundantly compute
//          alpha (one barrier total, no serial t==0 section; gate constants
//          arrive via uniform scalar loads).
//  Pass 2: out = f2 + a0*d, f2 re-read hits L2/L3 (just fetched), d from LDS.

constexpr int Dk  = 4096;
constexpr int Hk  = 7;
constexpr int NTH = 256;
constexpr int VPT = 4;   // float4 chunks per thread: 4*4*256 = 4096
constexpr size_t WS_NEEDED = (size_t)Hk * Dk * sizeof(float) + 16 * sizeof(float);

// ws layout: [0 .. 7*4096)  W1T (j-major: W1T[j*4096 + d] = W1[d*7 + j])
//            [7*4096 +0..7) b1
//            [+7 .. +14)    s_j = sum_k W2[j,k]
//            [+14]          sum(b2)
__global__ void gating_prep(const float* __restrict__ W1,
                            const float* __restrict__ b1,
                            const float* __restrict__ W2,
                            const float* __restrict__ b2,
                            float* __restrict__ ws)
{
    const int d = blockIdx.x * NTH + threadIdx.x;
    if (d < Dk) {
        #pragma unroll
        for (int j = 0; j < Hk; ++j)
            ws[j * Dk + d] = W1[d * Hk + j];
    }
    if (blockIdx.x == 0 && threadIdx.x == 0) {
        float* c = ws + Hk * Dk;
        #pragma unroll
        for (int j = 0; j < Hk; ++j) {
            c[j] = b1[j];
            float s = 0.f;
            #pragma unroll
            for (int k = 0; k < Hk; ++k) s += W2[j * Hk + k];
            c[Hk + j] = s;
        }
        float sb2 = 0.f;
        #pragma unroll
        for (int k = 0; k < Hk; ++k) sb2 += b2[k];
        c[14] = sb2;
    }
}

__global__ __launch_bounds__(NTH, 6)
void gating_fused(const float* __restrict__ f1,
                  const float* __restrict__ f2,
                  const float* __restrict__ W1T,   // [7][4096] in ws
                  const float* __restrict__ gc,    // b1[7], s[7], sb2
                  float* __restrict__ out)
{
    __shared__ float sdiff[Dk];            // f1 - f2 (16 KB)
    __shared__ float red[4][2 * Hk];

    const int row = blockIdx.x;
    const int t   = threadIdx.x;
    const long long base = (long long)row * Dk;

    const float4* __restrict__ f1v = reinterpret_cast<const float4*>(f1 + base);
    const float4* __restrict__ f2v = reinterpret_cast<const float4*>(f2 + base);
    const float4* __restrict__ wTv = reinterpret_cast<const float4*>(W1T);
    float4* __restrict__ sdv = reinterpret_cast<float4*>(sdiff);

    float acc1[Hk], acc2[Hk];
    #pragma unroll
    for (int j = 0; j < Hk; ++j) { acc1[j] = 0.f; acc2[j] = 0.f; }

    // ---- Pass 1: stream + accumulate ----
    #pragma unroll
    for (int k = 0; k < VPT; ++k) {
        const int vi = k * NTH + t;
        const float4 a = f1v[vi];
        const float4 b = f2v[vi];
        float4 d;
        d.x = a.x - b.x; d.y = a.y - b.y; d.z = a.z - b.z; d.w = a.w - b.w;
        sdv[vi] = d;
        #pragma unroll
        for (int j = 0; j < Hk; ++j) {
            const float4 w = wTv[j * (Dk / 4) + vi];
            acc1[j] = fmaf(a.x, w.x, fmaf(a.y, w.y, fmaf(a.z, w.z, fmaf(a.w, w.w, acc1[j]))));
            acc2[j] = fmaf(b.x, w.x, fmaf(b.y, w.y, fmaf(b.z, w.z, fmaf(b.w, w.w, acc2[j]))));
        }
    }

    // ---- wave shuffle reduction of the 14 partials ----
    #pragma unroll
    for (int j = 0; j < Hk; ++j) {
        #pragma unroll
        for (int off = 32; off >= 1; off >>= 1) {
            acc1[j] += __shfl_down(acc1[j], off);
            acc2[j] += __shfl_down(acc2[j], off);
        }
    }

    const int wave = t >> 6;
    const int lane = t & 63;
    if (lane == 0) {
        #pragma unroll
        for (int j = 0; j < Hk; ++j) {
            red[wave][j]      = acc1[j];
            red[wave][Hk + j] = acc2[j];
        }
    }
    __syncthreads();

    // ---- all threads redundantly compute alpha (no 2nd barrier) ----
    float l1 = 0.f, l2 = 0.f;
    #pragma unroll
    for (int j = 0; j < Hk; ++j) {
        const float b1j = gc[j];         // uniform -> scalar loads
        const float sj  = gc[Hk + j];
        float h1 = red[0][j] + red[1][j] + red[2][j] + red[3][j] + b1j;
        float h2 = red[0][Hk + j] + red[1][Hk + j] + red[2][Hk + j]
                 + red[3][Hk + j] + b1j;
        l1 = fmaf(fmaxf(h1, 0.f), sj, l1);
        l2 = fmaf(fmaxf(h2, 0.f), sj, l2);
    }
    const float sb2 = gc[14];
    l1 = (l1 + sb2) * (1.f / 7.f);
    l2 = (l2 + sb2) * (1.f / 7.f);
    const float a0 = 1.f / (1.f + expf(l2 - l1));   // softmax weight of expert 1

    // ---- Pass 2: out = f2 + a0*(f1-f2) ----
    float4* __restrict__ ov = reinterpret_cast<float4*>(out + base);
    #pragma unroll
    for (int k = 0; k < VPT; ++k) {
        const int vi = k * NTH + t;
        const float4 b = f2v[vi];        // L2/L3 hit (just fetched)
        const float4 d = sdv[vi];
        float4 o;
        o.x = fmaf(a0, d.x, b.x);
        o.y = fmaf(a0, d.y, b.y);
        o.z = fmaf(a0, d.z, b.z);
        o.w = fmaf(a0, d.w, b.w);
        ov[vi] = o;
    }
}

// Fallback (ws too small): direct-W1 path from R1 (known correct).
__global__ __launch_bounds__(NTH, 4)
void gating_fused_direct(const float* __restrict__ f1,
                         const float* __restrict__ f2,
                         const float* __restrict__ W1,
                         const float* __restrict__ b1,
                         const float* __restrict__ W2,
                         const float* __restrict__ b2,
                         float* __restrict__ out)
{
    const int row = blockIdx.x;
    const int t   = threadIdx.x;
    const long long base = (long long)row * Dk;

    const float4* f1v = reinterpret_cast<const float4*>(f1 + base);
    const float4* f2v = reinterpret_cast<const float4*>(f2 + base);

    float4 r1[VPT], r2[VPT];
    float acc1[Hk], acc2[Hk];
    #pragma unroll
    for (int j = 0; j < Hk; ++j) { acc1[j] = 0.f; acc2[j] = 0.f; }

    #pragma unroll
    for (int k = 0; k < VPT; ++k) {
        const int vi = k * NTH + t;
        r1[k] = f1v[vi];
        r2[k] = f2v[vi];
        const float4* wv = reinterpret_cast<const float4*>(W1 + (long long)vi * 28);
        float4 w4[7];
        #pragma unroll
        for (int q = 0; q < 7; ++q) w4[q] = wv[q];
        const float* ws = reinterpret_cast<const float*>(w4);
        const float* x1 = reinterpret_cast<const float*>(&r1[k]);
        const float* x2 = reinterpret_cast<const float*>(&r2[k]);
        #pragma unroll
        for (int r = 0; r < 4; ++r)
            #pragma unroll
            for (int j = 0; j < Hk; ++j) {
                acc1[j] = fmaf(x1[r], ws[r * 7 + j], acc1[j]);
                acc2[j] = fmaf(x2[r], ws[r * 7 + j], acc2[j]);
            }
    }
    #pragma unroll
    for (int j = 0; j < Hk; ++j)
        #pragma unroll
        for (int off = 32; off >= 1; off >>= 1) {
            acc1[j] += __shfl_down(acc1[j], off);
            acc2[j] += __shfl_down(acc2[j], off);
        }

    __shared__ float red[4][2 * Hk];
    __shared__ float alpha[2];
    const int wave = t >> 6;
    const int lane = t & 63;
    if (lane == 0)
        #pragma unroll
        for (int j = 0; j < Hk; ++j) {
            red[wave][j]      = acc1[j];
            red[wave][Hk + j] = acc2[j];
        }
    __syncthreads();

    if (t == 0) {
        float l1 = 0.f, l2 = 0.f;
        #pragma unroll
        for (int j = 0; j < Hk; ++j) {
            float h1 = red[0][j] + red[1][j] + red[2][j] + red[3][j] + b1[j];
            float h2 = red[0][Hk + j] + red[1][Hk + j] + red[2][Hk + j]
                     + red[3][Hk + j] + b1[j];
            float s = 0.f;
            #pragma unroll
            for (int k2 = 0; k2 < Hk; ++k2) s += W2[j * Hk + k2];
            l1 = fmaf(fmaxf(h1, 0.f), s, l1);
            l2 = fmaf(fmaxf(h2, 0.f), s, l2);
        }
        float sb2 = 0.f;
        #pragma unroll
        for (int k2 = 0; k2 < Hk; ++k2) sb2 += b2[k2];
        l1 = (l1 + sb2) * (1.f / 7.f);
        l2 = (l2 + sb2) * (1.f / 7.f);
        const float a0 = 1.f / (1.f + expf(l2 - l1));
        alpha[0] = a0;
        alpha[1] = 1.f - a0;
    }
    __syncthreads();

    const float a0 = alpha[0];
    const float a1 = alpha[1];
    float4* ov = reinterpret_cast<float4*>(out + base);
    #pragma unroll
    for (int k = 0; k < VPT; ++k) {
        const int vi = k * NTH + t;
        float4 o;
        o.x = a0 * r1[k].x + a1 * r2[k].x;
        o.y = a0 * r1[k].y + a1 * r2[k].y;
        o.z = a0 * r1[k].z + a1 * r2[k].z;
        o.w = a0 * r1[k].w + a1 * r2[k].w;
        ov[vi] = o;
    }
}

extern "C" void kernel_launch(void* const* d_in, const int* in_sizes, int n_in,
                              void* d_out, int out_size, void* d_ws, size_t ws_size,
                              hipStream_t stream) {
    const float* f1 = (const float*)d_in[0];
    const float* f2 = (const float*)d_in[1];
    const float* W1 = (const float*)d_in[2];
    const float* b1 = (const float*)d_in[3];
    const float* W2 = (const float*)d_in[4];
    const float* b2 = (const float*)d_in[5];
    float* out = (float*)d_out;
    const int rows = in_sizes[0] / Dk;   // 16384

    if (ws_size >= WS_NEEDED) {
        float* ws = (float*)d_ws;
        gating_prep<<<(Dk + NTH - 1) / NTH, NTH, 0, stream>>>(W1, b1, W2, b2, ws);
        gating_fused<<<rows, NTH, 0, stream>>>(f1, f2, ws, ws + Hk * Dk, out);
    } else {
        gating_fused_direct<<<rows, NTH, 0, stream>>>(f1, f2, W1, b1, W2, b2, out);
    }
}